// Round 8
// baseline (21.975 us; speedup 1.0000x reference)
//
#include <hip/hip_runtime.h>

// Problem constants (from reference setup_inputs):
//   pred_emb:   (N=2, C=80, H=512, W=512) float32
//   gt_objmask: (N=2, K=32, H=512, W=512) bool (1 byte/elem)
//   gt_classes: (N=2, K=32) int32
#define N_IMG 2
#define K_OBJ 32
#define C_CH  80
#define HW    (512 * 512)
#define NK    (N_IMG * K_OBJ)

#define BPN 32                    // blocks per (n,k)
#define BT  256                   // threads per block
#define DEPTH 8                   // float4 per thread
// per nk: HW/4 = 65536 float4; per block: 2048 float4 = 8/thread (stride BT).
// 2048 blocks x 4 waves = 8192 waves = exactly all-resident (32 waves/CU).

// ws layout: ws[blk][comp][nk], comp in {cnt,s,s2}; 32*3*64 floats = 24 KB.
// Every slot is written every call by partial_kernel, so no zeroing needed.

__global__ __launch_bounds__(BT) void partial_kernel(
    const float* __restrict__ pred,
    const unsigned char* __restrict__ mask,
    const int* __restrict__ classes,
    float* __restrict__ ws)
{
    const int nk  = blockIdx.x / BPN;
    const int blk = blockIdx.x % BPN;
    const int n   = nk / K_OBJ;
    const int c   = classes[nk];

    const float4* __restrict__ embv =
        (const float4*)(pred + (size_t)(n * C_CH + c) * HW);
    const unsigned int* __restrict__ mv32 =
        (const unsigned int*)(mask + (size_t)nk * HW);

    const int base = blk * (BT * DEPTH) + threadIdx.x;

    // Issue ALL loads before any consumption; every instruction is
    // unit-stride across the wave: emb 16 B/lane, mask 4 B/lane.
    float4 e[DEPTH];
    unsigned int m[DEPTH];
    #pragma unroll
    for (int q = 0; q < DEPTH; ++q) {
        const int idx = base + q * BT;
        e[q] = embv[idx];
        m[q] = mv32[idx];
    }

    // Sum mask dwords bytewise first (bytes <= 8 < 256), one mul-shift at end.
    unsigned int msum = 0;
    #pragma unroll
    for (int q = 0; q < DEPTH; ++q) msum += m[q];
    unsigned int cnt_i = (msum * 0x01010101u) >> 24;

    float s = 0.0f, s2 = 0.0f;
#define ACCB(w, b, ev) do {                                  \
        float v_ = (((w) >> (8*(b))) & 1u) ? (ev) : 0.0f;    \
        s += v_; s2 = fmaf(v_, (ev), s2);                    \
    } while (0)
    #pragma unroll
    for (int q = 0; q < DEPTH; ++q) {
        ACCB(m[q], 0, e[q].x);
        ACCB(m[q], 1, e[q].y);
        ACCB(m[q], 2, e[q].z);
        ACCB(m[q], 3, e[q].w);
    }
#undef ACCB

    float cnt = (float)cnt_i;
    #pragma unroll
    for (int off = 32; off > 0; off >>= 1) {
        cnt += __shfl_down(cnt, off);
        s   += __shfl_down(s,   off);
        s2  += __shfl_down(s2,  off);
    }

    __shared__ float sm[3][BT / 64];
    const int lane = threadIdx.x & 63;
    const int wv   = threadIdx.x >> 6;
    if (lane == 0) { sm[0][wv] = cnt; sm[1][wv] = s; sm[2][wv] = s2; }
    __syncthreads();
    if (threadIdx.x == 0) {
        float tc = 0.f, ts = 0.f, t2 = 0.f;
        #pragma unroll
        for (int w = 0; w < BT / 64; ++w) {
            tc += sm[0][w]; ts += sm[1][w]; t2 += sm[2][w];
        }
        float* dst = ws + (size_t)blk * 3 * NK;
        dst[0 * NK + nk] = tc;
        dst[1 * NK + nk] = ts;
        dst[2 * NK + nk] = t2;
    }
}

// 256 threads: 4 groups x 64 nk; group g sums blocks [8g, 8g+8), then LDS
// combine; first wave (64 threads) does mean/var + the tiny epilogue.
__global__ __launch_bounds__(256) void finalize(
    const float* __restrict__ ws,
    const int* __restrict__ classes,
    float* __restrict__ out)
{
    const int t  = threadIdx.x;
    const int nk = t & 63;
    const int g  = t >> 6;               // 0..3

    float cnt = 0.f, s = 0.f, s2 = 0.f;
    #pragma unroll
    for (int b = 0; b < BPN / 4; ++b) {
        const float* src = ws + (size_t)(g * (BPN / 4) + b) * 3 * NK;
        cnt += src[0 * NK + nk];
        s   += src[1 * NK + nk];
        s2  += src[2 * NK + nk];
    }

    __shared__ float pc[4][NK], ps[4][NK], p2[4][NK];
    pc[g][nk] = cnt; ps[g][nk] = s; p2[g][nk] = s2;
    __syncthreads();

    __shared__ float smean[NK];
    __shared__ int   scls[NK];
    float mean = 0.f, var = 0.f;
    if (t < NK) {
        float fc = pc[0][t] + pc[1][t] + pc[2][t] + pc[3][t];
        float fs = ps[0][t] + ps[1][t] + ps[2][t] + ps[3][t];
        float f2 = p2[0][t] + p2[1][t] + p2[2][t] + p2[3][t];
        const bool valid = fc > 0.0f;
        const float safe = valid ? fc : 1.0f;
        mean = valid ? fs / safe : 0.0f;
        var  = valid ? f2 / safe - mean * mean : 0.0f;
        smean[t] = mean;
        scls[t]  = classes[t];
    }
    __syncthreads();

    if (t < NK) {
        const int j  = t & 31;           // instance within image
        const int nb = t & 32;           // image base (0 or 32)
        float part = (mean * mean + var) * (1.0f / K_OBJ);  // reg+intra share
        const int cj = scls[t];
        for (int k = j + 1; k < K_OBJ; ++k) {
            if (scls[nb + k] == cj) {
                float d = mean - smean[nb + k];
                float val = 1.0f - d * d;
                part += (val > 0.0f) ? val : 0.0f;
            }
        }
        #pragma unroll
        for (int off = 32; off > 0; off >>= 1) part += __shfl_down(part, off);
        if (t == 0) out[0] = part * (0.1f / N_IMG);
    }
}

extern "C" void kernel_launch(void* const* d_in, const int* in_sizes, int n_in,
                              void* d_out, int out_size, void* d_ws, size_t ws_size,
                              hipStream_t stream) {
    const float* pred = (const float*)d_in[0];
    const unsigned char* mask = (const unsigned char*)d_in[1];
    const int* classes = (const int*)d_in[2];
    float* out = (float*)d_out;
    float* ws = (float*)d_ws;

    partial_kernel<<<NK * BPN, BT, 0, stream>>>(pred, mask, classes, ws);
    finalize<<<1, 256, 0, stream>>>(ws, classes, out);
}